// Round 3
// baseline (320.646 us; speedup 1.0000x reference)
//
#include <hip/hip_runtime.h>
#include <hip/hip_bf16.h>
#include <cstdint>

typedef __attribute__((ext_vector_type(8))) short short8v;
typedef __attribute__((ext_vector_type(4))) float f32x4;

#define B_  8
#define H_  8
#define NQ_ 1024
#define NK_ 1024
#define DM_ 512
#define DK_ 64

__device__ __forceinline__ unsigned short f2bf(float f) {
  unsigned u = __float_as_uint(f);
  u += 0x7FFF + ((u >> 16) & 1);
  return (unsigned short)(u >> 16);
}

typedef const __attribute__((address_space(1))) unsigned int* gas1_t;
typedef __attribute__((address_space(3))) unsigned int* las3_t;
__device__ __forceinline__ void gload16(const void* g, void* l) {
  __builtin_amdgcn_global_load_lds((gas1_t)g, (las3_t)l, 16, 0, 0);
}

// ---------------- f32 -> bf16 bulk convert, 3 tensors in one launch ----------------
__global__ __launch_bounds__(256) void conv_bf16_3(
    const float* __restrict__ s0, const float* __restrict__ s1, const float* __restrict__ s2,
    unsigned short* __restrict__ d0, unsigned short* __restrict__ d1, unsigned short* __restrict__ d2) {
  int z = blockIdx.y;
  const float* src = z == 0 ? s0 : z == 1 ? s1 : s2;
  unsigned short* dst = z == 0 ? d0 : z == 1 ? d1 : d2;
  int i = blockIdx.x * 256 + threadIdx.x;  // 524288 chunks of 8
  const float4* s4 = (const float4*)src + (size_t)i * 2;
  float4 a = s4[0], b = s4[1];
  short8v o;
  o[0] = (short)f2bf(a.x); o[1] = (short)f2bf(a.y);
  o[2] = (short)f2bf(a.z); o[3] = (short)f2bf(a.w);
  o[4] = (short)f2bf(b.x); o[5] = (short)f2bf(b.y);
  o[6] = (short)f2bf(b.z); o[7] = (short)f2bf(b.w);
  *(short8v*)(dst + (size_t)i * 8) = o;
}

// ---------------- W [512][512] f32 -> Wt bf16 transposed, 4 matrices, LDS-tiled ----------------
__global__ __launch_bounds__(256) void transpose_w4(
    const float* __restrict__ s0, const float* __restrict__ s1,
    const float* __restrict__ s2, const float* __restrict__ s3,
    unsigned short* __restrict__ d0, unsigned short* __restrict__ d1,
    unsigned short* __restrict__ d2, unsigned short* __restrict__ d3) {
  __shared__ float tile[64][65];
  int z = blockIdx.z;
  const float* src = z == 0 ? s0 : z == 1 ? s1 : z == 2 ? s2 : s3;
  unsigned short* dst = z == 0 ? d0 : z == 1 ? d1 : z == 2 ? d2 : d3;
  int t = threadIdx.x, tx = t & 63, ty = t >> 6;
  int r0 = blockIdx.y * 64, c0 = blockIdx.x * 64;
#pragma unroll
  for (int r = ty; r < 64; r += 4)
    tile[r][tx] = src[(size_t)(r0 + r) * 512 + c0 + tx];
  __syncthreads();
#pragma unroll
  for (int r = ty; r < 64; r += 4)
    dst[(size_t)(c0 + r) * 512 + r0 + tx] = f2bf(tile[tx][r]);
}

// ---------------- bf16 GEMM body (m97-style: global_load_lds, linear LDS) ----------------
// C[m][n] = sum_k A[m][k]*Bt[n][k] + bias[n].  M=8192, N=512, K=512.
// BM=BN=128, BK=32, 4 waves (2x2), wave computes 64x64.
// Staging: 4x global_load_lds per K-step (2 passes per operand, 64 rows per pass):
//   lane l of wave w -> LDS byte offset pass*4096 + w*1024 + l*16
//   = row (pass*64 + w*16 + (l>>2)), col (l&3)*8  -- linear tile order.
// mode 0: q layout [B,H,N,64] bf16 ; 1: k layout ; 2: vT layout [B,H,64,N] bf16 ; 3: f32 out
__device__ __forceinline__ void gemm_body(
    const unsigned short* __restrict__ A,
    const unsigned short* __restrict__ Bt,
    const float* __restrict__ bias,
    void* __restrict__ outp, int mode, int bx, int by) {
  const int K = 512;
  __shared__ unsigned short As[128 * 32];
  __shared__ unsigned short Bs[128 * 32];
  int t = threadIdx.x, wave = t >> 6, lane = t & 63;
  int wr = wave >> 1, wc = wave & 1;
  int row0 = bx * 128, col0 = by * 128;
  int srow = t >> 2, scol = (t & 3) * 8;  // rows 0..63 (pass 0), +64 (pass 1)
  const unsigned short* ga = A + (size_t)(row0 + srow) * K + scol;
  const unsigned short* gb = Bt + (size_t)(col0 + srow) * K + scol;
  unsigned short* lA0 = As + wave * 512;         // rows 0..63
  unsigned short* lA1 = As + 2048 + wave * 512;  // rows 64..127
  unsigned short* lB0 = Bs + wave * 512;
  unsigned short* lB1 = Bs + 2048 + wave * 512;
  int l15 = lane & 15, lk = (lane >> 4) * 8;
  f32x4 acc[4][4] = {};
  for (int kb = 0; kb < K; kb += 32) {
    __syncthreads();
    gload16(ga + kb, lA0);
    gload16(ga + (size_t)64 * K + kb, lA1);
    gload16(gb + kb, lB0);
    gload16(gb + (size_t)64 * K + kb, lB1);
    __syncthreads();
    short8v af[4], bf[4];
#pragma unroll
    for (int i = 0; i < 4; ++i)
      af[i] = *(const short8v*)(As + (wr * 64 + i * 16 + l15) * 32 + lk);
#pragma unroll
    for (int j = 0; j < 4; ++j)
      bf[j] = *(const short8v*)(Bs + (wc * 64 + j * 16 + l15) * 32 + lk);
#pragma unroll
    for (int i = 0; i < 4; ++i)
#pragma unroll
      for (int j = 0; j < 4; ++j)
        acc[i][j] = __builtin_amdgcn_mfma_f32_16x16x32_bf16(af[i], bf[j], acc[i][j], 0, 0, 0);
  }
  int lr = (lane >> 4) * 4;
#pragma unroll
  for (int i = 0; i < 4; ++i) {
#pragma unroll
    for (int j = 0; j < 4; ++j) {
      int col = col0 + wc * 64 + j * 16 + l15;
      float bb = bias[col];
#pragma unroll
      for (int r = 0; r < 4; ++r) {
        int m = row0 + wr * 64 + i * 16 + lr + r;
        float v = acc[i][j][r] + bb;
        if (mode == 3) {
          ((float*)outp)[(size_t)m * 512 + col] = v;
        } else {
          int b = m >> 10, n = m & 1023, h = col >> 6, d = col & 63;
          unsigned short bw = f2bf(v);
          if (mode == 2)
            ((unsigned short*)outp)[(((size_t)b * H_ + h) * DK_ + d) * NK_ + n] = bw;
          else
            ((unsigned short*)outp)[(((size_t)b * H_ + h) * NQ_ + n) * DK_ + d] = bw;
        }
      }
    }
  }
}

__global__ __launch_bounds__(256) void gemm_qkv(
    const unsigned short* __restrict__ A0, const unsigned short* __restrict__ A1,
    const unsigned short* __restrict__ A2,
    const unsigned short* __restrict__ B0, const unsigned short* __restrict__ B1,
    const unsigned short* __restrict__ B2,
    const float* __restrict__ c0, const float* __restrict__ c1, const float* __restrict__ c2,
    unsigned short* __restrict__ o0, unsigned short* __restrict__ o1,
    unsigned short* __restrict__ o2) {
  int z = blockIdx.z;
  const unsigned short* A = z == 0 ? A0 : z == 1 ? A1 : A2;
  const unsigned short* Bt = z == 0 ? B0 : z == 1 ? B1 : B2;
  const float* bias = z == 0 ? c0 : z == 1 ? c1 : c2;
  unsigned short* o = z == 0 ? o0 : z == 1 ? o1 : o2;
  gemm_body(A, Bt, bias, (void*)o, z, blockIdx.x, blockIdx.y);
}

__global__ __launch_bounds__(256) void gemm_out(
    const unsigned short* __restrict__ A, const unsigned short* __restrict__ Bt,
    const float* __restrict__ bias, float* __restrict__ o) {
  gemm_body(A, Bt, bias, (void*)o, 3, blockIdx.x, blockIdx.y);
}

// ---------------- fused attention ----------------
// grid: B*H*(NQ/64) = 1024 blocks, 256 threads (4 waves).
// Per 64-q-row block, 16 k-tiles of 64. K/V fragments read direct from global (L2-resident).
// S-tile round-trips through LDS f32 so mask/unnorm I/O is row-contiguous (float4/int4).
__global__ __launch_bounds__(256) void attn_fused(
    const unsigned short* __restrict__ qw,   // [B,H,NQ,64] bf16
    const unsigned short* __restrict__ kw,   // [B,H,NK,64] bf16
    const unsigned short* __restrict__ vtw,  // [B,H,64,NK] bf16 (V transposed)
    const int* __restrict__ mask,            // [B,NQ,NK] int32
    float* __restrict__ unnorm,              // [B,H,NQ,NK] f32 (output 1)
    unsigned short* __restrict__ ctx) {      // [B,NQ,512] bf16
  __shared__ float Sf[64 * 68];              // raw scores, f32
  __shared__ unsigned short Ps[64 * 72];     // P in bf16, MFMA-A layout
  __shared__ float alphaS[64];               // per-row rescale (reused for 1/lsum)
  int bid = blockIdx.x;
  int qb = bid & 15, h = (bid >> 4) & 7, b = bid >> 7;
  int t = threadIdx.x, wave = t >> 6, lane = t & 63;
  int l15 = lane & 15, lg = lane >> 4;
  const unsigned short* qp = qw + (((size_t)b * H_ + h) * NQ_ + qb * 64) * 64;
  const unsigned short* kp = kw + ((size_t)b * H_ + h) * NK_ * 64;
  const unsigned short* vp = vtw + ((size_t)b * H_ + h) * 64 * NK_;
  // Q fragments: direct global (one-time)
  short8v aq0 = *(const short8v*)(qp + (size_t)(wave * 16 + l15) * 64 + lg * 8);
  short8v aq1 = *(const short8v*)(qp + (size_t)(wave * 16 + l15) * 64 + 32 + lg * 8);
  // masked-pass ownership: 16-lane group (t>>4) owns rows p*16+(t>>4), 4 cols each
  int msub = t >> 4;        // 0..15
  int mcol = (t & 15) * 4;  // 0..60
  float mrun[4] = {-INFINITY, -INFINITY, -INFINITY, -INFINITY};
  float lrun[4] = {0.f, 0.f, 0.f, 0.f};
  f32x4 oacc[4] = {};
  for (int kb = 0; kb < 16; ++kb) {
    // ---- QK^T (K frags direct from global) ----
    f32x4 s[4] = {};
#pragma unroll
    for (int j = 0; j < 4; ++j) {
      const unsigned short* kt = kp + (size_t)(kb * 64 + j * 16 + l15) * 64 + lg * 8;
      short8v bk0 = *(const short8v*)(kt);
      short8v bk1 = *(const short8v*)(kt + 32);
      s[j] = __builtin_amdgcn_mfma_f32_16x16x32_bf16(aq0, bk0, s[j], 0, 0, 0);
      s[j] = __builtin_amdgcn_mfma_f32_16x16x32_bf16(aq1, bk1, s[j], 0, 0, 0);
    }
#pragma unroll
    for (int j = 0; j < 4; ++j)
#pragma unroll
      for (int r = 0; r < 4; ++r)
        Sf[(wave * 16 + lg * 4 + r) * 68 + j * 16 + l15] = s[j][r];
    __syncthreads();
    // ---- masked pass: row-contiguous I/O + online softmax ----
#pragma unroll
    for (int p = 0; p < 4; ++p) {
      int rl = p * 16 + msub;
      int gq = qb * 64 + rl;
      f32x4 sv = *(const f32x4*)(Sf + rl * 68 + mcol);
      float s0 = sv[0] * 0.125f, s1 = sv[1] * 0.125f, s2 = sv[2] * 0.125f, s3 = sv[3] * 0.125f;
      size_t coff = (size_t)kb * 64 + mcol;
      float4 st; st.x = s0; st.y = s1; st.z = s2; st.w = s3;
      *(float4*)(unnorm + ((size_t)(b * H_ + h) * NQ_ + gq) * NK_ + coff) = st;
      int4 mk = *(const int4*)(mask + ((size_t)b * NQ_ + gq) * NK_ + coff);
      float e0 = mk.x ? s0 : -INFINITY;
      float e1 = mk.y ? s1 : -INFINITY;
      float e2 = mk.z ? s2 : -INFINITY;
      float e3 = mk.w ? s3 : -INFINITY;
      float tmax = fmaxf(fmaxf(e0, e1), fmaxf(e2, e3));
      tmax = fmaxf(tmax, __shfl_xor(tmax, 1));
      tmax = fmaxf(tmax, __shfl_xor(tmax, 2));
      tmax = fmaxf(tmax, __shfl_xor(tmax, 4));
      tmax = fmaxf(tmax, __shfl_xor(tmax, 8));
      float mnew = fmaxf(mrun[p], tmax);
      float alpha = (mnew == -INFINITY) ? 1.0f : __expf(mrun[p] - mnew);
      mrun[p] = mnew;
      float p0 = (e0 == -INFINITY) ? 0.f : __expf(e0 - mnew);
      float p1 = (e1 == -INFINITY) ? 0.f : __expf(e1 - mnew);
      float p2 = (e2 == -INFINITY) ? 0.f : __expf(e2 - mnew);
      float p3 = (e3 == -INFINITY) ? 0.f : __expf(e3 - mnew);
      float ps = p0 + p1 + p2 + p3;
      ps += __shfl_xor(ps, 1);
      ps += __shfl_xor(ps, 2);
      ps += __shfl_xor(ps, 4);
      ps += __shfl_xor(ps, 8);
      lrun[p] = lrun[p] * alpha + ps;
      if ((t & 15) == 0) alphaS[rl] = alpha;
      ushort4 pb;
      pb.x = f2bf(p0); pb.y = f2bf(p1); pb.z = f2bf(p2); pb.w = f2bf(p3);
      *(ushort4*)(Ps + rl * 72 + mcol) = pb;
    }
    __syncthreads();
    // ---- PV (rescale then accumulate; V frags direct from global) ----
    float af_[4];
#pragma unroll
    for (int r = 0; r < 4; ++r) af_[r] = alphaS[wave * 16 + lg * 4 + r];
#pragma unroll
    for (int j = 0; j < 4; ++j)
#pragma unroll
      for (int r = 0; r < 4; ++r) oacc[j][r] *= af_[r];
#pragma unroll
    for (int ks = 0; ks < 2; ++ks) {
      short8v ap = *(const short8v*)(Ps + (size_t)(wave * 16 + l15) * 72 + ks * 32 + lg * 8);
#pragma unroll
      for (int j = 0; j < 4; ++j) {
        const unsigned short* vt = vp + (size_t)(j * 16 + l15) * NK_ + kb * 64 + ks * 32 + lg * 8;
        short8v bv = *(const short8v*)vt;
        oacc[j] = __builtin_amdgcn_mfma_f32_16x16x32_bf16(ap, bv, oacc[j], 0, 0, 0);
      }
    }
    __syncthreads();
  }
  // epilogue: 1/lsum via LDS handoff, then ctx write
#pragma unroll
  for (int p = 0; p < 4; ++p)
    if ((t & 15) == 0) alphaS[p * 16 + msub] = lrun[p] > 0.f ? 1.0f / lrun[p] : 0.0f;
  __syncthreads();
#pragma unroll
  for (int r = 0; r < 4; ++r) {
    float inv = alphaS[wave * 16 + lg * 4 + r];
    int n = qb * 64 + wave * 16 + lg * 4 + r;
    unsigned short* cp = ctx + ((size_t)b * NQ_ + n) * 512 + h * 64;
#pragma unroll
    for (int j = 0; j < 4; ++j) cp[j * 16 + l15] = f2bf(oacc[j][r] * inv);
  }
}

extern "C" void kernel_launch(void* const* d_in, const int* in_sizes, int n_in,
                              void* d_out, int out_size, void* d_ws, size_t ws_size,
                              hipStream_t stream) {
  const float* queries = (const float*)d_in[0];
  const float* keys    = (const float*)d_in[1];
  const float* values  = (const float*)d_in[2];
  const int*   amask   = (const int*)d_in[3];
  const float* Wq = (const float*)d_in[4];
  const float* bq = (const float*)d_in[5];
  const float* Wk = (const float*)d_in[6];
  const float* bk = (const float*)d_in[7];
  const float* Wv = (const float*)d_in[8];
  const float* bv = (const float*)d_in[9];
  const float* Wo = (const float*)d_in[10];
  const float* bo = (const float*)d_in[11];

  float* out_f = (float*)d_out;                    // [8,1024,512]
  float* unnorm = out_f + (size_t)B_ * NQ_ * DM_;  // [8,8,1024,1024]

  char* ws = (char*)d_ws;
  size_t off = 0;
  unsigned short* Xq  = (unsigned short*)(ws + off); off += (size_t)8192 * 512 * 2;
  unsigned short* Xk  = (unsigned short*)(ws + off); off += (size_t)8192 * 512 * 2;
  unsigned short* Xv  = (unsigned short*)(ws + off); off += (size_t)8192 * 512 * 2;
  unsigned short* Wqt = (unsigned short*)(ws + off); off += (size_t)512 * 512 * 2;
  unsigned short* Wkt = (unsigned short*)(ws + off); off += (size_t)512 * 512 * 2;
  unsigned short* Wvt = (unsigned short*)(ws + off); off += (size_t)512 * 512 * 2;
  unsigned short* Wot = (unsigned short*)(ws + off); off += (size_t)512 * 512 * 2;
  unsigned short* qws  = (unsigned short*)(ws + off); off += (size_t)8192 * 512 * 2;
  unsigned short* kws  = (unsigned short*)(ws + off); off += (size_t)8192 * 512 * 2;
  unsigned short* vtws = (unsigned short*)(ws + off); off += (size_t)8192 * 512 * 2;
  unsigned short* ctx  = (unsigned short*)(ws + off); off += (size_t)8192 * 512 * 2;

  conv_bf16_3<<<dim3(2048, 3), 256, 0, stream>>>(queries, keys, values, Xq, Xk, Xv);
  transpose_w4<<<dim3(8, 8, 4), 256, 0, stream>>>(Wq, Wk, Wv, Wo, Wqt, Wkt, Wvt, Wot);

  gemm_qkv<<<dim3(64, 4, 3), 256, 0, stream>>>(Xq, Xk, Xv, Wqt, Wkt, Wvt,
                                               bq, bk, bv, qws, kws, vtws);

  attn_fused<<<1024, 256, 0, stream>>>(qws, kws, vtws, amask, unnorm, ctx);

  gemm_out<<<dim3(64, 4), 256, 0, stream>>>(ctx, Wot, bo, out_f);
}

// Round 4
// 269.000 us; speedup vs baseline: 1.1920x; 1.1920x over previous
//
#include <hip/hip_runtime.h>
#include <hip/hip_bf16.h>
#include <cstdint>

typedef __attribute__((ext_vector_type(8))) short short8v;
typedef __attribute__((ext_vector_type(4))) float f32x4;

#define B_  8
#define H_  8
#define NQ_ 1024
#define NK_ 1024
#define DM_ 512
#define DK_ 64

__device__ __forceinline__ unsigned short f2bf(float f) {
  unsigned u = __float_as_uint(f);
  u += 0x7FFF + ((u >> 16) & 1);
  return (unsigned short)(u >> 16);
}

typedef const __attribute__((address_space(1))) unsigned int* gas1_t;
typedef __attribute__((address_space(3))) unsigned int* las3_t;
__device__ __forceinline__ void gload16(const void* g, void* l) {
  __builtin_amdgcn_global_load_lds((gas1_t)g, (las3_t)l, 16, 0, 0);
}

// ---------------- f32 -> bf16 bulk convert, 3 tensors in one launch ----------------
__global__ __launch_bounds__(256) void conv_bf16_3(
    const float* __restrict__ s0, const float* __restrict__ s1, const float* __restrict__ s2,
    unsigned short* __restrict__ d0, unsigned short* __restrict__ d1, unsigned short* __restrict__ d2) {
  int z = blockIdx.y;
  const float* src = z == 0 ? s0 : z == 1 ? s1 : s2;
  unsigned short* dst = z == 0 ? d0 : z == 1 ? d1 : d2;
  int i = blockIdx.x * 256 + threadIdx.x;  // 524288 chunks of 8
  const float4* s4 = (const float4*)src + (size_t)i * 2;
  float4 a = s4[0], b = s4[1];
  short8v o;
  o[0] = (short)f2bf(a.x); o[1] = (short)f2bf(a.y);
  o[2] = (short)f2bf(a.z); o[3] = (short)f2bf(a.w);
  o[4] = (short)f2bf(b.x); o[5] = (short)f2bf(b.y);
  o[6] = (short)f2bf(b.z); o[7] = (short)f2bf(b.w);
  *(short8v*)(dst + (size_t)i * 8) = o;
}

// ---------------- W [512][512] f32 -> Wt bf16 transposed, 4 matrices, LDS-tiled ----------------
__global__ __launch_bounds__(256) void transpose_w4(
    const float* __restrict__ s0, const float* __restrict__ s1,
    const float* __restrict__ s2, const float* __restrict__ s3,
    unsigned short* __restrict__ d0, unsigned short* __restrict__ d1,
    unsigned short* __restrict__ d2, unsigned short* __restrict__ d3) {
  __shared__ float tile[64][65];
  int z = blockIdx.z;
  const float* src = z == 0 ? s0 : z == 1 ? s1 : z == 2 ? s2 : s3;
  unsigned short* dst = z == 0 ? d0 : z == 1 ? d1 : z == 2 ? d2 : d3;
  int t = threadIdx.x, tx = t & 63, ty = t >> 6;
  int r0 = blockIdx.y * 64, c0 = blockIdx.x * 64;
#pragma unroll
  for (int r = ty; r < 64; r += 4)
    tile[r][tx] = src[(size_t)(r0 + r) * 512 + c0 + tx];
  __syncthreads();
#pragma unroll
  for (int r = ty; r < 64; r += 4)
    dst[(size_t)(c0 + r) * 512 + r0 + tx] = f2bf(tile[tx][r]);
}

// ---------------- bf16 GEMM body (m97-style: global_load_lds, linear LDS) ----------------
__device__ __forceinline__ void gemm_body(
    const unsigned short* __restrict__ A,
    const unsigned short* __restrict__ Bt,
    const float* __restrict__ bias,
    void* __restrict__ outp, int mode, int bx, int by) {
  const int K = 512;
  __shared__ unsigned short As[128 * 32];
  __shared__ unsigned short Bs[128 * 32];
  int t = threadIdx.x, wave = t >> 6, lane = t & 63;
  int wr = wave >> 1, wc = wave & 1;
  int row0 = bx * 128, col0 = by * 128;
  int srow = t >> 2, scol = (t & 3) * 8;
  const unsigned short* ga = A + (size_t)(row0 + srow) * K + scol;
  const unsigned short* gb = Bt + (size_t)(col0 + srow) * K + scol;
  unsigned short* lA0 = As + wave * 512;
  unsigned short* lA1 = As + 2048 + wave * 512;
  unsigned short* lB0 = Bs + wave * 512;
  unsigned short* lB1 = Bs + 2048 + wave * 512;
  int l15 = lane & 15, lk = (lane >> 4) * 8;
  f32x4 acc[4][4] = {};
  for (int kb = 0; kb < K; kb += 32) {
    __syncthreads();
    gload16(ga + kb, lA0);
    gload16(ga + (size_t)64 * K + kb, lA1);
    gload16(gb + kb, lB0);
    gload16(gb + (size_t)64 * K + kb, lB1);
    __syncthreads();
    short8v af[4], bf[4];
#pragma unroll
    for (int i = 0; i < 4; ++i)
      af[i] = *(const short8v*)(As + (wr * 64 + i * 16 + l15) * 32 + lk);
#pragma unroll
    for (int j = 0; j < 4; ++j)
      bf[j] = *(const short8v*)(Bs + (wc * 64 + j * 16 + l15) * 32 + lk);
#pragma unroll
    for (int i = 0; i < 4; ++i)
#pragma unroll
      for (int j = 0; j < 4; ++j)
        acc[i][j] = __builtin_amdgcn_mfma_f32_16x16x32_bf16(af[i], bf[j], acc[i][j], 0, 0, 0);
  }
  int lr = (lane >> 4) * 4;
#pragma unroll
  for (int i = 0; i < 4; ++i) {
#pragma unroll
    for (int j = 0; j < 4; ++j) {
      int col = col0 + wc * 64 + j * 16 + l15;
      float bb = bias[col];
#pragma unroll
      for (int r = 0; r < 4; ++r) {
        int m = row0 + wr * 64 + i * 16 + lr + r;
        float v = acc[i][j][r] + bb;
        if (mode == 3) {
          ((float*)outp)[(size_t)m * 512 + col] = v;
        } else {
          int b = m >> 10, n = m & 1023, h = col >> 6, d = col & 63;
          unsigned short bw = f2bf(v);
          if (mode == 2)
            ((unsigned short*)outp)[(((size_t)b * H_ + h) * DK_ + d) * NK_ + n] = bw;
          else
            ((unsigned short*)outp)[(((size_t)b * H_ + h) * NQ_ + n) * DK_ + d] = bw;
        }
      }
    }
  }
}

__global__ __launch_bounds__(256) void gemm_qkv(
    const unsigned short* __restrict__ A0, const unsigned short* __restrict__ A1,
    const unsigned short* __restrict__ A2,
    const unsigned short* __restrict__ B0, const unsigned short* __restrict__ B1,
    const unsigned short* __restrict__ B2,
    const float* __restrict__ c0, const float* __restrict__ c1, const float* __restrict__ c2,
    unsigned short* __restrict__ o0, unsigned short* __restrict__ o1,
    unsigned short* __restrict__ o2) {
  int z = blockIdx.z;
  const unsigned short* A = z == 0 ? A0 : z == 1 ? A1 : A2;
  const unsigned short* Bt = z == 0 ? B0 : z == 1 ? B1 : B2;
  const float* bias = z == 0 ? c0 : z == 1 ? c1 : c2;
  unsigned short* o = z == 0 ? o0 : z == 1 ? o1 : o2;
  gemm_body(A, Bt, bias, (void*)o, z, blockIdx.x, blockIdx.y);
}

__global__ __launch_bounds__(256) void gemm_out(
    const unsigned short* __restrict__ A, const unsigned short* __restrict__ Bt,
    const float* __restrict__ bias, float* __restrict__ o) {
  gemm_body(A, Bt, bias, (void*)o, 3, blockIdx.x, blockIdx.y);
}

// ---------------- fused attention (barrier-free, swapped-QK^T, reg-prefetched) ----------------
// grid: B*H*(NQ/64) = 1024 blocks, 256 threads = 4 INDEPENDENT waves.
// Wave w owns q-rows [qb*64 + w*16, +16). Per k-tile (64 keys):
//   S^T = mfma(Kfrag, Qfrag): lane (l15,lg) holds S[k=j*16+lg*4+r][q=l15]
//   -> per-lane float4 unnorm store, int4 mask load, in-register online softmax
//   -> P via per-wave private LDS (A-frag relayout), PV = mfma(Pfrag, VTfrag).
// K-frags + mask double-buffered in regs (issued one tile ahead); V-frags issued at tile start.
#define PSLD 88  // P row stride (elems): 176 B = 16B-aligned, 2-way banks
__global__ __launch_bounds__(256, 2) void attn_fused(
    const unsigned short* __restrict__ qw,   // [B,H,NQ,64] bf16
    const unsigned short* __restrict__ kw,   // [B,H,NK,64] bf16
    const unsigned short* __restrict__ vtw,  // [B,H,64,NK] bf16 (V transposed)
    const int* __restrict__ mask,            // [B,NQ,NK] int32
    float* __restrict__ unnorm,              // [B,H,NQ,NK] f32 (output 1)
    unsigned short* __restrict__ ctx) {      // [B,NQ,512] bf16
  __shared__ unsigned short Ps[4][16 * PSLD];
  int bid = blockIdx.x;
  int qb = bid & 15, h = (bid >> 4) & 7, b = bid >> 7;
  int t = threadIdx.x, wave = t >> 6, lane = t & 63;
  int l15 = lane & 15, lg = lane >> 4;
  const unsigned short* qp = qw + (((size_t)b * H_ + h) * NQ_ + qb * 64 + wave * 16) * 64;
  const unsigned short* kfp = kw + ((size_t)b * H_ + h) * NK_ * 64 + (size_t)l15 * 64 + lg * 8;
  const unsigned short* vfp = vtw + ((size_t)b * H_ + h) * 64 * NK_ + (size_t)l15 * NK_ + lg * 8;
  int qrow = qb * 64 + wave * 16 + l15;  // this lane's softmax q-row
  float* up = unnorm + ((size_t)(b * H_ + h) * NQ_ + qrow) * NK_ + lg * 4;
  const int* mp = mask + ((size_t)b * NQ_ + qrow) * NK_ + lg * 4;
  unsigned short* psw = Ps[wave] + l15 * PSLD;
  // Q B-frags (one-time)
  short8v aq0 = *(const short8v*)(qp + (size_t)l15 * 64 + lg * 8);
  short8v aq1 = *(const short8v*)(qp + (size_t)l15 * 64 + 32 + lg * 8);

  short8v kfA[4][2], kfB[4][2];
  int4 mkA[4], mkB[4];
#pragma unroll
  for (int j = 0; j < 4; ++j) {
    kfA[j][0] = *(const short8v*)(kfp + (size_t)(j * 16) * 64);
    kfA[j][1] = *(const short8v*)(kfp + (size_t)(j * 16) * 64 + 32);
    mkA[j] = *(const int4*)(mp + j * 16);
  }
  float mrun = -INFINITY, lrun = 0.f;
  f32x4 oacc[4] = {};

#define ATTN_TILE(KB, KFC, KFN, MKC, MKN)                                          \
  {                                                                                \
    int kn = ((KB) + 1) & 15; /* wrap: harmless re-read of tile 0 at the end */    \
    _Pragma("unroll")                                                              \
    for (int j = 0; j < 4; ++j) {                                                  \
      KFN[j][0] = *(const short8v*)(kfp + (size_t)(kn * 64 + j * 16) * 64);        \
      KFN[j][1] = *(const short8v*)(kfp + (size_t)(kn * 64 + j * 16) * 64 + 32);   \
      MKN[j] = *(const int4*)(mp + kn * 64 + j * 16);                              \
    }                                                                              \
    short8v vf[4][2];                                                              \
    _Pragma("unroll")                                                              \
    for (int j = 0; j < 4; ++j) {                                                  \
      vf[j][0] = *(const short8v*)(vfp + (size_t)(j * 16) * NK_ + (KB) * 64);      \
      vf[j][1] = *(const short8v*)(vfp + (size_t)(j * 16) * NK_ + (KB) * 64 + 32); \
    }                                                                              \
    f32x4 s[4] = {};                                                               \
    _Pragma("unroll")                                                              \
    for (int j = 0; j < 4; ++j) {                                                  \
      s[j] = __builtin_amdgcn_mfma_f32_16x16x32_bf16(KFC[j][0], aq0, s[j], 0, 0, 0); \
      s[j] = __builtin_amdgcn_mfma_f32_16x16x32_bf16(KFC[j][1], aq1, s[j], 0, 0, 0); \
    }                                                                              \
    float p_[4][4];                                                                \
    float pmax = -INFINITY;                                                        \
    _Pragma("unroll")                                                              \
    for (int j = 0; j < 4; ++j) {                                                  \
      float4 st;                                                                   \
      st.x = s[j][0] * 0.125f; st.y = s[j][1] * 0.125f;                            \
      st.z = s[j][2] * 0.125f; st.w = s[j][3] * 0.125f;                            \
      *(float4*)(up + (size_t)(KB) * 64 + j * 16) = st;                            \
      p_[j][0] = MKC[j].x ? st.x : -INFINITY;                                      \
      p_[j][1] = MKC[j].y ? st.y : -INFINITY;                                      \
      p_[j][2] = MKC[j].z ? st.z : -INFINITY;                                      \
      p_[j][3] = MKC[j].w ? st.w : -INFINITY;                                      \
      pmax = fmaxf(pmax, fmaxf(fmaxf(p_[j][0], p_[j][1]), fmaxf(p_[j][2], p_[j][3]))); \
    }                                                                              \
    pmax = fmaxf(pmax, __shfl_xor(pmax, 16));                                      \
    pmax = fmaxf(pmax, __shfl_xor(pmax, 32));                                      \
    float mnew = fmaxf(mrun, pmax);                                                \
    float alpha = (mnew == -INFINITY) ? 1.0f : __expf(mrun - mnew);                \
    float psum = 0.f;                                                              \
    _Pragma("unroll")                                                              \
    for (int j = 0; j < 4; ++j) {                                                  \
      _Pragma("unroll")                                                            \
      for (int r = 0; r < 4; ++r) {                                                \
        float pv = (p_[j][r] == -INFINITY) ? 0.f : __expf(p_[j][r] - mnew);        \
        psum += pv;                                                                \
        p_[j][r] = pv;                                                             \
      }                                                                            \
    }                                                                              \
    psum += __shfl_xor(psum, 16);                                                  \
    psum += __shfl_xor(psum, 32);                                                  \
    lrun = lrun * alpha + psum;                                                    \
    mrun = mnew;                                                                   \
    _Pragma("unroll")                                                              \
    for (int j = 0; j < 4; ++j) {                                                  \
      ushort4 pb;                                                                  \
      pb.x = f2bf(p_[j][0]); pb.y = f2bf(p_[j][1]);                                \
      pb.z = f2bf(p_[j][2]); pb.w = f2bf(p_[j][3]);                                \
      *(ushort4*)(psw + j * 16 + lg * 4) = pb;                                     \
    }                                                                              \
    short8v ap0 = *(const short8v*)(psw + lg * 8);                                 \
    short8v ap1 = *(const short8v*)(psw + 32 + lg * 8);                            \
    float av0 = __shfl(alpha, lg * 4 + 0), av1 = __shfl(alpha, lg * 4 + 1);        \
    float av2 = __shfl(alpha, lg * 4 + 2), av3 = __shfl(alpha, lg * 4 + 3);        \
    _Pragma("unroll")                                                              \
    for (int j = 0; j < 4; ++j) {                                                  \
      oacc[j][0] *= av0; oacc[j][1] *= av1;                                        \
      oacc[j][2] *= av2; oacc[j][3] *= av3;                                        \
    }                                                                              \
    _Pragma("unroll")                                                              \
    for (int j = 0; j < 4; ++j) {                                                  \
      oacc[j] = __builtin_amdgcn_mfma_f32_16x16x32_bf16(ap0, vf[j][0], oacc[j], 0, 0, 0); \
      oacc[j] = __builtin_amdgcn_mfma_f32_16x16x32_bf16(ap1, vf[j][1], oacc[j], 0, 0, 0); \
    }                                                                              \
  }

  for (int kb = 0; kb < 16; kb += 2) {
    ATTN_TILE(kb, kfA, kfB, mkA, mkB);
    ATTN_TILE(kb + 1, kfB, kfA, mkB, mkA);
  }
#undef ATTN_TILE

  // epilogue: inv-lsum for q-rows lg*4+r via shfl, write ctx
  float lv0 = __shfl(lrun, lg * 4 + 0), lv1 = __shfl(lrun, lg * 4 + 1);
  float lv2 = __shfl(lrun, lg * 4 + 2), lv3 = __shfl(lrun, lg * 4 + 3);
  float iv[4];
  iv[0] = lv0 > 0.f ? 1.0f / lv0 : 0.0f;
  iv[1] = lv1 > 0.f ? 1.0f / lv1 : 0.0f;
  iv[2] = lv2 > 0.f ? 1.0f / lv2 : 0.0f;
  iv[3] = lv3 > 0.f ? 1.0f / lv3 : 0.0f;
#pragma unroll
  for (int r = 0; r < 4; ++r) {
    int n = qb * 64 + wave * 16 + lg * 4 + r;
    unsigned short* cp = ctx + ((size_t)b * NQ_ + n) * 512 + h * 64;
#pragma unroll
    for (int j = 0; j < 4; ++j) cp[j * 16 + l15] = f2bf(oacc[j][r] * iv[r]);
  }
}

extern "C" void kernel_launch(void* const* d_in, const int* in_sizes, int n_in,
                              void* d_out, int out_size, void* d_ws, size_t ws_size,
                              hipStream_t stream) {
  const float* queries = (const float*)d_in[0];
  const float* keys    = (const float*)d_in[1];
  const float* values  = (const float*)d_in[2];
  const int*   amask   = (const int*)d_in[3];
  const float* Wq = (const float*)d_in[4];
  const float* bq = (const float*)d_in[5];
  const float* Wk = (const float*)d_in[6];
  const float* bk = (const float*)d_in[7];
  const float* Wv = (const float*)d_in[8];
  const float* bv = (const float*)d_in[9];
  const float* Wo = (const float*)d_in[10];
  const float* bo = (const float*)d_in[11];

  float* out_f = (float*)d_out;                    // [8,1024,512]
  float* unnorm = out_f + (size_t)B_ * NQ_ * DM_;  // [8,8,1024,1024]

  char* ws = (char*)d_ws;
  size_t off = 0;
  unsigned short* Xq  = (unsigned short*)(ws + off); off += (size_t)8192 * 512 * 2;
  unsigned short* Xk  = (unsigned short*)(ws + off); off += (size_t)8192 * 512 * 2;
  unsigned short* Xv  = (unsigned short*)(ws + off); off += (size_t)8192 * 512 * 2;
  unsigned short* Wqt = (unsigned short*)(ws + off); off += (size_t)512 * 512 * 2;
  unsigned short* Wkt = (unsigned short*)(ws + off); off += (size_t)512 * 512 * 2;
  unsigned short* Wvt = (unsigned short*)(ws + off); off += (size_t)512 * 512 * 2;
  unsigned short* Wot = (unsigned short*)(ws + off); off += (size_t)512 * 512 * 2;
  unsigned short* qws  = (unsigned short*)(ws + off); off += (size_t)8192 * 512 * 2;
  unsigned short* kws  = (unsigned short*)(ws + off); off += (size_t)8192 * 512 * 2;
  unsigned short* vtws = (unsigned short*)(ws + off); off += (size_t)8192 * 512 * 2;
  unsigned short* ctx  = (unsigned short*)(ws + off); off += (size_t)8192 * 512 * 2;

  conv_bf16_3<<<dim3(2048, 3), 256, 0, stream>>>(queries, keys, values, Xq, Xk, Xv);
  transpose_w4<<<dim3(8, 8, 4), 256, 0, stream>>>(Wq, Wk, Wv, Wo, Wqt, Wkt, Wvt, Wot);

  gemm_qkv<<<dim3(64, 4, 3), 256, 0, stream>>>(Xq, Xk, Xv, Wqt, Wkt, Wvt,
                                               bq, bk, bv, qws, kws, vtws);

  attn_fused<<<1024, 256, 0, stream>>>(qws, kws, vtws, amask, unnorm, ctx);

  gemm_out<<<dim3(64, 4), 256, 0, stream>>>(ctx, Wot, bo, out_f);
}